// Round 4
// baseline (62.132 us; speedup 1.0000x reference)
//
#include <hip/hip_runtime.h>

#define NC 1024
#define NS 32
#define DD 512
#define MARGIN 0.3f

// Halving butterfly over 16 per-thread values across 64 lanes.
// Step mask m pairs lanes l, l^m; lane with (l&m) set keeps the hi half.
// After masks 1,2,4,8 each lane holds the 16-lane-group sum of element
// j = bitrev4(lane&15); masks 16,32 complete the 64-lane sum.
__device__ __forceinline__ float reduce_cols16(float v[16], int lane) {
#pragma unroll
    for (int m = 1, half = 8; m <= 8; m <<= 1, half >>= 1) {
#pragma unroll
        for (int i = 0; i < half; ++i) {
            float lo = v[i], hi = v[i + half];
            float send = (lane & m) ? lo : hi;
            float recv = __shfl_xor(send, m);
            v[i] = (lane & m) ? (hi + recv) : (lo + recv);
        }
    }
    float r = v[0];
    r += __shfl_xor(r, 16);
    r += __shfl_xor(r, 32);
    return r;
}

// One block per class, 256 threads (R2's proven codegen shape: the 128 KB
// class tile is register-resident, each HBM byte read exactly once).
// g = t>>7 picks sample parity (rows s = 2j+g), col4 = t&127 the thread's
// float4 column; consecutive lanes -> consecutive float4s (coalesced).
// Final mean over classes is fused: last block to finish reduces the
// per-class losses (counter in d_ws zeroed by a memset node each call).
__global__ __launch_bounds__(256) void ccl_fused(const float* __restrict__ emb,
                                                 float* __restrict__ cls,
                                                 unsigned* __restrict__ cnt,
                                                 float* __restrict__ out) {
    const int c = blockIdx.x;
    const int t = threadIdx.x;
    const int g = t >> 7;
    const int col4 = t & 127;
    const int lane = t & 63;
    const int wv = t >> 6;
    const float4* posv = (const float4*)(emb + (size_t)c * (2 * NS * DD));
    const float4* negv = posv + NS * DD / 4;

    __shared__ float4 s_part[2][128];
    __shared__ float s_wap[4][16];
    __shared__ float s_wnd[4][16];
    __shared__ float s_fin[4];
    __shared__ unsigned s_old;

    // ---- load: 16 pos rows then 16 neg rows (rows s = 2j+g) ----
    float4 p[16], n[16];
#pragma unroll
    for (int j = 0; j < 16; ++j) p[j] = posv[(2 * j + g) * (DD / 4) + col4];
#pragma unroll
    for (int j = 0; j < 16; ++j) n[j] = negv[(2 * j + g) * (DD / 4) + col4];

    // ---- anchor: thread-local column sum over 16 rows, LDS combine ----
    float4 acc = p[0];
#pragma unroll
    for (int j = 1; j < 16; ++j) {
        acc.x += p[j].x; acc.y += p[j].y; acc.z += p[j].z; acc.w += p[j].w;
    }
    s_part[g][col4] = acc;
    __syncthreads();
    float4 a;
    {
        float4 x0 = s_part[0][col4], x1 = s_part[1][col4];
        a.x = (x0.x + x1.x) * (1.f / NS);
        a.y = (x0.y + x1.y) * (1.f / NS);
        a.z = (x0.z + x1.z) * (1.f / NS);
        a.w = (x0.w + x1.w) * (1.f / NS);
    }

    // ---- per-(sample, column) squared-diff partials ----
    float apc[16], ndc[16];
#pragma unroll
    for (int j = 0; j < 16; ++j) {
        float dx = p[j].x - a.x, dy = p[j].y - a.y, dz = p[j].z - a.z, dw = p[j].w - a.w;
        apc[j] = dx * dx + dy * dy + dz * dz + dw * dw;
        dx = n[j].x - a.x; dy = n[j].y - a.y; dz = n[j].z - a.z; dw = n[j].w - a.w;
        ndc[j] = dx * dx + dy * dy + dz * dz + dw * dw;
    }

    // ---- reduce across the wave's 64 columns (17 shuffles per array) ----
    float rap = reduce_cols16(apc, lane);
    float rnd = reduce_cols16(ndc, lane);
    if (lane < 16) {
        const int jm = ((lane & 1) << 3) | ((lane & 2) << 1) | ((lane & 4) >> 1) | ((lane & 8) >> 3);
        s_wap[wv][jm] = rap;
        s_wnd[wv][jm] = rnd;
    }
    __syncthreads();

    // ---- per-class min + hinge (lanes 0-31 of wave 0) ----
    if (t < NS) {
        const int sg = t & 1, sj = t >> 1;  // sample s = 2*sj + sg
        float ap = s_wap[2 * sg][sj] + s_wap[2 * sg + 1][sj];
        float nd = s_wnd[2 * sg][sj] + s_wnd[2 * sg + 1][sj];
        float an = nd;
#pragma unroll
        for (int m = 1; m < 32; m <<= 1) an = fminf(an, __shfl_xor(an, m));
        float l = fmaxf(ap - an + MARGIN, 0.f);
#pragma unroll
        for (int m = 1; m < 32; m <<= 1) l += __shfl_xor(l, m);
        if (t == 0) {
            __hip_atomic_store(&cls[c], l, __ATOMIC_RELAXED, __HIP_MEMORY_SCOPE_AGENT);
            s_old = __hip_atomic_fetch_add(cnt, 1u, __ATOMIC_ACQ_REL, __HIP_MEMORY_SCOPE_AGENT);
        }
    }
    __syncthreads();

    // ---- last block computes the deterministic fixed-order mean ----
    if (s_old == NC - 1) {
        float v = __hip_atomic_load(&cls[t], __ATOMIC_ACQUIRE, __HIP_MEMORY_SCOPE_AGENT) +
                  __hip_atomic_load(&cls[t + 256], __ATOMIC_ACQUIRE, __HIP_MEMORY_SCOPE_AGENT) +
                  __hip_atomic_load(&cls[t + 512], __ATOMIC_ACQUIRE, __HIP_MEMORY_SCOPE_AGENT) +
                  __hip_atomic_load(&cls[t + 768], __ATOMIC_ACQUIRE, __HIP_MEMORY_SCOPE_AGENT);
#pragma unroll
        for (int m = 1; m < 64; m <<= 1) v += __shfl_xor(v, m);
        if (lane == 0) s_fin[wv] = v;
        __syncthreads();
        if (t == 0)
            out[0] = (s_fin[0] + s_fin[1] + s_fin[2] + s_fin[3]) * (1.f / NC);
    }
}

extern "C" void kernel_launch(void* const* d_in, const int* in_sizes, int n_in,
                              void* d_out, int out_size, void* d_ws, size_t ws_size,
                              hipStream_t stream) {
    const float* emb = (const float*)d_in[0];       // (2*NC*NS, DD) f32
    unsigned* cnt = (unsigned*)d_ws;                // completion counter
    float* cls = (float*)((char*)d_ws + 256);       // NC per-class losses
    float* out = (float*)d_out;                     // 1 float
    hipMemsetAsync(cnt, 0, 4, stream);              // zero counter each call
    ccl_fused<<<NC, 256, 0, stream>>>(emb, cls, cnt, out);
}